// Round 1
// baseline (48.675 us; speedup 1.0000x reference)
//
#include <hip/hip_runtime.h>

// loss = (mean_i dot(real_i, fake_i) + 1) / 2
//      = (dot(x[0:N/2], x[N/2:N]) / (N/2/1024... ) ... ) -- concretely:
// sim_i = sum_d x[i,d]*x[i+B/2,d]; loss = (sum_i sim_i / (B/2) + 1)/2.
// Row-major => sum_i sim_i = flat dot of first half vs second half.

__global__ __launch_bounds__(256) void dot_partial_kernel(
    const float4* __restrict__ a, const float4* __restrict__ b,
    float* __restrict__ partials, long n4) {
    long tid = (long)blockIdx.x * blockDim.x + threadIdx.x;
    long stride = (long)gridDim.x * blockDim.x;
    float acc = 0.0f;
    for (long i = tid; i < n4; i += stride) {
        float4 x = a[i];
        float4 y = b[i];
        acc += x.x * y.x + x.y * y.y + x.z * y.z + x.w * y.w;
    }
    // wave-64 reduction
    #pragma unroll
    for (int off = 32; off > 0; off >>= 1)
        acc += __shfl_down(acc, off, 64);
    __shared__ float s[4];
    int lane = threadIdx.x & 63;
    int wave = threadIdx.x >> 6;
    if (lane == 0) s[wave] = acc;
    __syncthreads();
    if (threadIdx.x == 0) {
        float t = s[0] + s[1] + s[2] + s[3];
        partials[blockIdx.x] = t;
    }
}

__global__ __launch_bounds__(256) void finalize_kernel(
    const float* __restrict__ partials, float* __restrict__ out,
    int nblocks, float inv_count) {
    float acc = 0.0f;
    for (int i = threadIdx.x; i < nblocks; i += blockDim.x)
        acc += partials[i];
    #pragma unroll
    for (int off = 32; off > 0; off >>= 1)
        acc += __shfl_down(acc, off, 64);
    __shared__ float s[4];
    int lane = threadIdx.x & 63;
    int wave = threadIdx.x >> 6;
    if (lane == 0) s[wave] = acc;
    __syncthreads();
    if (threadIdx.x == 0) {
        float total = s[0] + s[1] + s[2] + s[3];
        out[0] = (total * inv_count + 1.0f) * 0.5f;
    }
}

extern "C" void kernel_launch(void* const* d_in, const int* in_sizes, int n_in,
                              void* d_out, int out_size, void* d_ws, size_t ws_size,
                              hipStream_t stream) {
    const float* x = (const float*)d_in[0];
    long n = (long)in_sizes[0];          // 65536 * 1024
    long half = n / 2;                   // 33554432
    long n4 = half / 4;                  // 8388608 float4 pairs
    long rows = half / 1024;             // 32768 rows

    const float4* a = (const float4*)x;
    const float4* b = (const float4*)(x + half);
    float* partials = (float*)d_ws;

    const int BLOCK = 256;
    const int GRID = 2048;  // 256 CUs x 8 blocks; grid-stride covers the rest

    dot_partial_kernel<<<GRID, BLOCK, 0, stream>>>(a, b, partials, n4);
    finalize_kernel<<<1, BLOCK, 0, stream>>>(partials, (float*)d_out, GRID,
                                             1.0f / (float)rows);
}